// Round 8
// baseline (130.851 us; speedup 1.0000x reference)
//
#include <hip/hip_runtime.h>

#define DD 256
#define BB 8
#define NA 360

typedef _Float16 half2_t __attribute__((ext_vector_type(2)));

#if defined(__has_builtin)
#if __has_builtin(__builtin_elementwise_fma)
#define PKFMA(a, b, c) __builtin_elementwise_fma((a), (b), (c))
#endif
#endif
#ifndef PKFMA
#define PKFMA(a, b, c) ((a) * (b) + (c))
#endif

__device__ __forceinline__ half2_t h2(unsigned u) {
    return __builtin_bit_cast(half2_t, u);
}
__device__ __forceinline__ half2_t bcast2(float w) {   // v_cvt_pkrtz (w,w)
    return __builtin_bit_cast(half2_t, __builtin_amdgcn_cvt_pkrtz(w, w));
}
__device__ __forceinline__ unsigned pk_f16(float a, float b) {
    unsigned short ua = __builtin_bit_cast(unsigned short, (_Float16)a);
    unsigned short ub = __builtin_bit_cast(unsigned short, (_Float16)b);
    return (unsigned)ua | ((unsigned)ub << 16);
}

// ---- pack: (B,1,D,D) fp32 -> f16x8/pixel pN + transposed pT ---------------
// 256 blocks (16x16 tiles) so pack saturates the 256 CUs.
__global__ __launch_bounds__(256) void pack_f16(const float* __restrict__ x,
                                                uint4* __restrict__ pN,
                                                uint4* __restrict__ pT) {
    __shared__ uint4 t[16][17];
    const int tx = threadIdx.x & 15;
    const int ty = threadIdx.x >> 4;              // 0..15
    const int x0 = (blockIdx.x & 15) * 16;
    const int y0 = (blockIdx.x >> 4) * 16;

    const int pix = (y0 + ty) * DD + x0 + tx;
    uint4 v;
    v.x = pk_f16(x[0 * DD * DD + pix], x[1 * DD * DD + pix]);
    v.y = pk_f16(x[2 * DD * DD + pix], x[3 * DD * DD + pix]);
    v.z = pk_f16(x[4 * DD * DD + pix], x[5 * DD * DD + pix]);
    v.w = pk_f16(x[6 * DD * DD + pix], x[7 * DD * DD + pix]);
    pN[pix] = v;                                   // coalesced
    t[ty][tx] = v;
    __syncthreads();
    // pT[xx*D+yy] = img[yy][xx]
    pT[(x0 + ty) * DD + y0 + tx] = t[tx][ty];      // coalesced
}

// ---- radon: grid (360, 4 wsegs x 2 h-halves); 4 waves = h-phases ----------
// Inner loop identical to R7 (bitwise-same weights). Each block covers
// 64 w x 128 h; two blocks/output combine via atomicAdd (memset-0 base).
__global__ __launch_bounds__(256) void radon_pk(const uint4* __restrict__ pN,
                                                const uint4* __restrict__ pT,
                                                float* __restrict__ out) {
    const int a    = blockIdx.x;            // angle
    const int wseg = blockIdx.y & 3;        // 0..3
    const int hh   = blockIdx.y >> 2;       // h-half 0..1
    const int g    = threadIdx.x >> 6;      // wave = h-phase 0..3
    const int lane = threadIdx.x & 63;
    const int w    = wseg * 64 + lane;

    const float ang = (float)a * 0.5f;
    const float t = ang * 0.017453292519943295f;
    const float s = sinf(t);
    const float c = cosf(t);

    const float uw  = (float)w - 127.5f;
    const float axN = fmaf(c, uw, 127.5f);
    const float ayN = fmaf(s, uw, 127.5f);

    const uint4* __restrict__ P;
    float ax, dx, ay, dy;                    // inner = ax+dx*uh, row = ay+dy*uh
    if (fabsf(s) <= fabsf(c)) { P = pN; ax = axN; dx = -s; ay = ayN; dy = c;  }
    else                      { P = pT; ax = ayN; dx = c;  ay = axN; dy = -s; }

    half2_t acc2[4];
#pragma unroll
    for (int j = 0; j < 4; ++j) acc2[j] = half2_t{(_Float16)0, (_Float16)0};

    const int hbase = hh * 128 + g;          // h = hbase + 4*i, i<32
#pragma unroll 4
    for (int i = 0; i < 32; ++i) {
        const float uh = (float)(hbase + 4 * i) - 127.5f;
        const float ix = fmaf(dx, uh, ax);
        const float iy = fmaf(dy, uh, ay);
        const float x0f = floorf(ix), y0f = floorf(iy);
        const float wx1 = ix - x0f, wy1 = iy - y0f;
        const float wx0 = 1.f - wx1, wy0 = 1.f - wy1;
        const int x0 = (int)x0f, y0 = (int)y0f;
        const float vx0 = ((unsigned)x0 < 256u) ? wx0 : 0.f;
        const float vx1 = ((unsigned)(x0 + 1) < 256u) ? wx1 : 0.f;
        const float vy0 = ((unsigned)y0 < 256u) ? wy0 : 0.f;
        const float vy1 = ((unsigned)(y0 + 1) < 256u) ? wy1 : 0.f;
        const int x0c = min(max(x0, 0), 255);
        const int x1c = min(max(x0 + 1, 0), 255);
        const int y0c = min(max(y0, 0), 255);
        const int y1c = min(max(y0 + 1, 0), 255);

        const uint4 q00 = P[y0c * DD + x0c];
        const uint4 q10 = P[y0c * DD + x1c];
        const uint4 q01 = P[y1c * DD + x0c];
        const uint4 q11 = P[y1c * DD + x1c];

        const half2_t w00 = bcast2(vx0 * vy0);
        const half2_t w10 = bcast2(vx1 * vy0);
        const half2_t w01 = bcast2(vx0 * vy1);
        const half2_t w11 = bcast2(vx1 * vy1);

        acc2[0] = PKFMA(h2(q00.x), w00, acc2[0]);
        acc2[1] = PKFMA(h2(q00.y), w00, acc2[1]);
        acc2[2] = PKFMA(h2(q00.z), w00, acc2[2]);
        acc2[3] = PKFMA(h2(q00.w), w00, acc2[3]);
        acc2[0] = PKFMA(h2(q10.x), w10, acc2[0]);
        acc2[1] = PKFMA(h2(q10.y), w10, acc2[1]);
        acc2[2] = PKFMA(h2(q10.z), w10, acc2[2]);
        acc2[3] = PKFMA(h2(q10.w), w10, acc2[3]);
        acc2[0] = PKFMA(h2(q01.x), w01, acc2[0]);
        acc2[1] = PKFMA(h2(q01.y), w01, acc2[1]);
        acc2[2] = PKFMA(h2(q01.z), w01, acc2[2]);
        acc2[3] = PKFMA(h2(q01.w), w01, acc2[3]);
        acc2[0] = PKFMA(h2(q11.x), w11, acc2[0]);
        acc2[1] = PKFMA(h2(q11.y), w11, acc2[1]);
        acc2[2] = PKFMA(h2(q11.z), w11, acc2[2]);
        acc2[3] = PKFMA(h2(q11.w), w11, acc2[3]);
    }

    float acc[BB];
#pragma unroll
    for (int j = 0; j < 4; ++j) {
        acc[2 * j]     = (float)acc2[j].x;
        acc[2 * j + 1] = (float)acc2[j].y;
    }

    __shared__ float part[4][64][BB];        // 8 KB
#pragma unroll
    for (int b = 0; b < BB; b += 4)
        *(float4*)&part[g][lane][b] = make_float4(acc[b], acc[b + 1], acc[b + 2], acc[b + 3]);
    __syncthreads();

    const float sc = 1.0f / 256.0f;
#pragma unroll
    for (int k = 0; k < 2; ++k) {
        const int id = threadIdx.x + k * 256;  // (b, wl)
        const int b  = id >> 6;
        const int wl = id & 63;
        const float v = part[0][wl][b] + part[1][wl][b] + part[2][wl][b] + part[3][wl][b];
        atomicAdd(out + (size_t)b * NA * DD + (size_t)a * DD + wseg * 64 + wl, v * sc);
    }
}

// ---- fallback (ws too small): direct fp32 gather with atomics -------------
__global__ __launch_bounds__(256) void radon_direct(const float* __restrict__ x,
                                                    float* __restrict__ out) {
    const int a  = blockIdx.x;
    const int hc = blockIdx.y;
    const int w  = threadIdx.x;
    const float ang = (float)a * 0.5f;
    const float t = ang * 0.017453292519943295f;
    const float s = sinf(t);
    const float c = cosf(t);
    const float uw = (float)w - 127.5f;
    const float ax = fmaf(c, uw, 127.5f);
    const float ay = fmaf(s, uw, 127.5f);

    float acc[BB];
#pragma unroll
    for (int b = 0; b < BB; ++b) acc[b] = 0.f;

    const int h0 = hc * 32;
    for (int i = 0; i < 32; ++i) {
        const float uh = (float)(h0 + i) - 127.5f;
        const float ix = fmaf(-s, uh, ax);
        const float iy = fmaf(c, uh, ay);
        const float x0f = floorf(ix), y0f = floorf(iy);
        const float wx1 = ix - x0f, wy1 = iy - y0f;
        const float wx0 = 1.f - wx1, wy0 = 1.f - wy1;
        const int x0 = (int)x0f, y0 = (int)y0f;
        const float vx0 = ((unsigned)x0 < 256u) ? wx0 : 0.f;
        const float vx1 = ((unsigned)(x0 + 1) < 256u) ? wx1 : 0.f;
        const float vy0 = ((unsigned)y0 < 256u) ? wy0 : 0.f;
        const float vy1 = ((unsigned)(y0 + 1) < 256u) ? wy1 : 0.f;
        const int x0c = min(max(x0, 0), 255);
        const int x1c = min(max(x0 + 1, 0), 255);
        const int y0c = min(max(y0, 0), 255);
        const int y1c = min(max(y0 + 1, 0), 255);
        const float w00 = vx0 * vy0, w10 = vx1 * vy0;
        const float w01 = vx0 * vy1, w11 = vx1 * vy1;
        const int l00 = y0c * DD + x0c, l10 = y0c * DD + x1c;
        const int l01 = y1c * DD + x0c, l11 = y1c * DD + x1c;
#pragma unroll
        for (int b = 0; b < BB; ++b) {
            const float* ib = x + (size_t)b * DD * DD;
            acc[b] = fmaf(ib[l00], w00, acc[b]);
            acc[b] = fmaf(ib[l10], w10, acc[b]);
            acc[b] = fmaf(ib[l01], w01, acc[b]);
            acc[b] = fmaf(ib[l11], w11, acc[b]);
        }
    }

    const float sc = 1.0f / 256.0f;
    float* o = out + (size_t)a * DD + w;
#pragma unroll
    for (int b = 0; b < BB; ++b)
        atomicAdd(o + (size_t)b * NA * DD, acc[b] * sc);
}

extern "C" void kernel_launch(void* const* d_in, const int* in_sizes, int n_in,
                              void* d_out, int out_size, void* d_ws, size_t ws_size,
                              hipStream_t stream) {
    const float* x = (const float*)d_in[0];
    float* out = (float*)d_out;

    // atomic accumulation (2 writers/output) -> zero the poisoned output
    (void)hipMemsetAsync(d_out, 0, (size_t)out_size * sizeof(float), stream);

    const size_t need = 2ull * DD * DD * sizeof(uint4);  // 2 MiB
    if (ws_size >= need) {
        uint4* pN = (uint4*)d_ws;
        uint4* pT = pN + (size_t)DD * DD;
        pack_f16<<<256, 256, 0, stream>>>(x, pN, pT);
        radon_pk<<<dim3(NA, 8), 256, 0, stream>>>(pN, pT, out);
    } else {
        radon_direct<<<dim3(NA, 8), 256, 0, stream>>>(x, out);
    }
}